// Round 7
// baseline (209.160 us; speedup 1.0000x reference)
//
#include <hip/hip_runtime.h>
#include <hip/hip_bf16.h>

#define B_  8
#define C_  256
#define CI_ 64
#define N_  4096
#define KSPLIT 4
#define KTILES (N_ / 64 / KSPLIT)   // 16 key-tiles per split-slice

typedef short short8  __attribute__((ext_vector_type(8)));
typedef short sh4     __attribute__((ext_vector_type(4)));
typedef float floatx4 __attribute__((ext_vector_type(4)));

#define LOG2E 1.4426950408889634f

__device__ __forceinline__ unsigned short f2bf(float f) {
    unsigned u = __builtin_bit_cast(unsigned, f);
    u += 0x7FFFu + ((u >> 16) & 1u);   // round-to-nearest-even
    return (unsigned short)(u >> 16);
}
__device__ __forceinline__ float bf2f(unsigned short h) {
    unsigned u = ((unsigned)h) << 16;
    return __builtin_bit_cast(float, u);
}
__device__ __forceinline__ unsigned pk2(float a, float b) {
#if __has_builtin(__builtin_amdgcn_cvt_pk_bf16_f32)
    auto r = __builtin_amdgcn_cvt_pk_bf16_f32(a, b);
    return __builtin_bit_cast(unsigned, r);
#else
    return (unsigned)f2bf(a) | ((unsigned)f2bf(b) << 16);
#endif
}
__device__ __forceinline__ short8 pack8(float4 a, float4 b, float sc) {
    uint4 u = { pk2(a.x * sc, a.y * sc), pk2(a.z * sc, a.w * sc),
                pk2(b.x * sc, b.y * sc), pk2(b.z * sc, b.w * sc) };
    return __builtin_bit_cast(short8, u);
}
__device__ __forceinline__ floatx4 mfma32(short8 a, short8 b, floatx4 c) {
    return __builtin_amdgcn_mfma_f32_16x16x32_bf16(a, b, c, 0, 0, 0);
}
__device__ __forceinline__ floatx4 mfma16(sh4 a, sh4 b, floatx4 c) {
#if __has_builtin(__builtin_amdgcn_mfma_f32_16x16x16bf16_1k)
    return __builtin_amdgcn_mfma_f32_16x16x16bf16_1k(a, b, c, 0, 0, 0);
#else
    floatx4 d;
    asm("v_mfma_f32_16x16x16_bf16 %0, %1, %2, %3" : "=v"(d) : "v"(a), "v"(b), "v"(c));
    return d;
#endif
}

// ---------------------------------------------------------------------------
// Kernel 1: three 1x1-conv projections, one bf16 MFMA GEMM.  v5 rewrite:
//  - x tiles staged via COALESCED float4 reads (1/thread/k-step) with an
//    LDS transpose to [n][c] bf16; double-buffered, one barrier/iter.
//  - weights as B-fragments DIRECT from global (196KB, L2-hot), raw float4s
//    prefetched one k-step ahead; theta scaled by LOG2E at pack time.
//  - grid (128 n-tiles of 32, 8 b) = 1024 blocks of 256 thr.
// Each wave: 3 oc-frags (w*3..w*3+2 of 12) x 32 n (2 n-frags).
// ---------------------------------------------------------------------------
__global__ __launch_bounds__(256, 4) void proj_kernel(
    const float* __restrict__ x,
    const float* __restrict__ wg, const float* __restrict__ bg,
    const float* __restrict__ wt, const float* __restrict__ bt,
    const float* __restrict__ wp, const float* __restrict__ bp,
    unsigned short* __restrict__ gws,   // [B][CI][N]
    unsigned short* __restrict__ tws,   // [B][N][CI]  (theta, LOG2E-scaled)
    unsigned short* __restrict__ pws)   // [B][N][CI]
{
    constexpr int XK = 40;   // xt row stride (shorts): 80B, 16B-aligned
    constexpr int GS = 40;   // gt row stride
    __shared__ __align__(16) unsigned short xt[2][32 * XK];
    __shared__ __align__(16) unsigned short gt[64 * GS];

    const int t    = threadIdx.x;
    const int lane = t & 63;
    const int w    = t >> 6;
    const int l15  = lane & 15;
    const int quad = lane >> 4;
    const int n0   = blockIdx.x * 32;
    const int b    = blockIdx.y;

    // per-wave weight row pointers + scales (wave-uniform selector)
    const float* wrow[3];
    float wsc[3];
    int   frag[3];
#pragma unroll
    for (int of = 0; of < 3; ++of) {
        int fr = w * 3 + of;
        frag[of] = fr;
        if (fr < 4)      { wrow[of] = wg + (fr * 16 + l15) * C_;          wsc[of] = 1.0f; }
        else if (fr < 8) { wrow[of] = wt + ((fr - 4) * 16 + l15) * C_;    wsc[of] = LOG2E; }
        else             { wrow[of] = wp + ((fr - 8) * 16 + l15) * C_;    wsc[of] = 1.0f; }
    }

    floatx4 acc[3][2];
#pragma unroll
    for (int of = 0; of < 3; ++of)
#pragma unroll
        for (int nf = 0; nf < 2; ++nf) { floatx4 z = {0.f,0.f,0.f,0.f}; acc[of][nf] = z; }

    // x staging: thread reads one float4 (c-row xr, 4 n's) per k-step
    const int xr = t >> 3;      // c within slice 0..31
    const int xc = t & 7;       // n float4-group 0..7
    const float* xsrc = x + ((size_t)b * C_ + xr) * N_ + n0 + xc * 4;

    // prologue: tile 0
    float4 xv = *(const float4*)(xsrc);
    float4 wcur[3][2];
#pragma unroll
    for (int of = 0; of < 3; ++of) {
        wcur[of][0] = *(const float4*)(wrow[of] + quad * 8);
        wcur[of][1] = *(const float4*)(wrow[of] + quad * 8 + 4);
    }
    xt[0][(xc * 4 + 0) * XK + xr] = f2bf(xv.x);
    xt[0][(xc * 4 + 1) * XK + xr] = f2bf(xv.y);
    xt[0][(xc * 4 + 2) * XK + xr] = f2bf(xv.z);
    xt[0][(xc * 4 + 3) * XK + xr] = f2bf(xv.w);
    __syncthreads();

    for (int kk = 0; kk < 8; ++kk) {
        float4 xn;
        float4 wn[3][2];
        if (kk < 7) {
            xn = *(const float4*)(xsrc + (size_t)(kk + 1) * 32 * N_);
#pragma unroll
            for (int of = 0; of < 3; ++of) {
                wn[of][0] = *(const float4*)(wrow[of] + (kk + 1) * 32 + quad * 8);
                wn[of][1] = *(const float4*)(wrow[of] + (kk + 1) * 32 + quad * 8 + 4);
            }
        }

        short8 bf[3];
#pragma unroll
        for (int of = 0; of < 3; ++of)
            bf[of] = pack8(wcur[of][0], wcur[of][1], wsc[of]);

#pragma unroll
        for (int nf = 0; nf < 2; ++nf) {
            short8 af = *(const short8*)&xt[kk & 1][(nf * 16 + l15) * XK + quad * 8];
#pragma unroll
            for (int of = 0; of < 3; ++of)
                acc[of][nf] = mfma32(af, bf[of], acc[of][nf]);
        }

        if (kk < 7) {
            xt[(kk + 1) & 1][(xc * 4 + 0) * XK + xr] = f2bf(xn.x);
            xt[(kk + 1) & 1][(xc * 4 + 1) * XK + xr] = f2bf(xn.y);
            xt[(kk + 1) & 1][(xc * 4 + 2) * XK + xr] = f2bf(xn.z);
            xt[(kk + 1) & 1][(xc * 4 + 3) * XK + xr] = f2bf(xn.w);
        }
        __syncthreads();
#pragma unroll
        for (int of = 0; of < 3; ++of) { wcur[of][0] = wn[of][0]; wcur[of][1] = wn[of][1]; }
    }

    // epilogue: bias; g -> gt transpose, theta/phi -> direct (32B segments)
#pragma unroll
    for (int of = 0; of < 3; ++of) {
        const int fr = frag[of];
        if (fr < 4) {
            const int oc = fr * 16 + l15;
            const float bias = bg[oc];
#pragma unroll
            for (int nf = 0; nf < 2; ++nf)
#pragma unroll
                for (int r = 0; r < 4; ++r)
                    gt[oc * GS + nf * 16 + quad * 4 + r] = f2bf(acc[of][nf][r] + bias);
        } else {
            const int ci = (fr < 8) ? ((fr - 4) * 16 + l15) : ((fr - 8) * 16 + l15);
            const float bias = (fr < 8) ? bt[ci] * LOG2E : bp[ci];
            unsigned short* dst = (fr < 8) ? tws : pws;
#pragma unroll
            for (int nf = 0; nf < 2; ++nf)
#pragma unroll
                for (int r = 0; r < 4; ++r) {
                    int n = n0 + nf * 16 + quad * 4 + r;
                    dst[((size_t)b * N_ + n) * CI_ + ci] = f2bf(acc[of][nf][r] + bias);
                }
        }
    }
    __syncthreads();
    // coalesced g store: 64 ci rows x 32 n = 256 uint4, one per thread
    {
        int ci = t >> 2, cq = t & 3;
        uint4 v = *(const uint4*)&gt[ci * GS + cq * 8];
        *(uint4*)(gws + ((size_t)b * CI_ + ci) * N_ + n0 + cq * 8) = v;
    }
}

// ---------------------------------------------------------------------------
// Kernel 2: flash attention v6 — phase-separated K prefetch.
// Per iter: (A) S^T + exp consume ka regs; (B) ka regs RELOADED for tile
// j+1 (latency covered by phase C + barrier); (C) PV from LDS Vs.
// No Ks LDS; 32 Q rows/wave; double-buffered Vs; one barrier/iter; KSPLIT=4.
// ---------------------------------------------------------------------------
__global__ __launch_bounds__(256, 4) void attn_kernel(
    const unsigned short* __restrict__ gws,  // V^T [B][CI][N]
    const unsigned short* __restrict__ tws,  // Q   [B][N][CI] (LOG2E-scaled)
    const unsigned short* __restrict__ pws,  // K   [B][N][CI]
    unsigned short* __restrict__ Opart,      // [KSPLIT][B][N][CI] bf16
    float* __restrict__ lpart)               // [KSPLIT][B][N]
{
    constexpr int LDW = 72;
    __shared__ __align__(16) unsigned short Vs[2][64 * LDW];

    const int t    = threadIdx.x;
    const int lane = t & 63;
    const int w    = t >> 6;
    const int l15  = lane & 15;
    const int quad = lane >> 4;
    const int b    = blockIdx.x;
    const int q0   = blockIdx.y * 128;
    const int sp   = blockIdx.z;

    const int srow = t >> 3;   // 0..31 (ci)
    const int sc8  = t & 7;    // 16B column

    const unsigned short* kslice = pws + ((size_t)b * N_ + sp * (N_ / KSPLIT)) * CI_;
    const unsigned short* vbase  =
        gws + ((size_t)b * CI_ + srow) * N_ + sp * (N_ / KSPLIT) + sc8 * 8;

    // Q fragments (loop-invariant), 2 q-groups of 16 rows
    short8 qf[2][2];
#pragma unroll
    for (int qg = 0; qg < 2; ++qg) {
        const unsigned short* qrow =
            tws + ((size_t)b * N_ + q0 + w * 32 + qg * 16 + l15) * CI_;
        qf[qg][0] = *(const short8*)(qrow + quad * 8);
        qf[qg][1] = *(const short8*)(qrow + 32 + quad * 8);
    }

    // prologue: V tile 0 -> buf 0 ; ka <- tile 0
    short8 ka[4][2];
    {
        uint4 v0 = *(const uint4*)(vbase);
        uint4 v1 = *(const uint4*)(vbase + 32 * N_);
#pragma unroll
        for (int f = 0; f < 4; ++f) {
            ka[f][0] = *(const short8*)(kslice + (f * 16 + l15) * CI_ + quad * 8);
            ka[f][1] = *(const short8*)(kslice + (f * 16 + l15) * CI_ + 32 + quad * 8);
        }
        *(uint4*)&Vs[0][srow * LDW + sc8 * 8]        = v0;
        *(uint4*)&Vs[0][(srow + 32) * LDW + sc8 * 8] = v1;
    }
    __syncthreads();

    sh4 ones4;
#pragma unroll
    for (int j4 = 0; j4 < 4; ++j4) ones4[j4] = (short)0x3F80;   // bf16 1.0

    floatx4 Oacc[2][4], lacc[2];
    { floatx4 z = {0.f, 0.f, 0.f, 0.f};
      lacc[0] = z; lacc[1] = z;
#pragma unroll
      for (int qg = 0; qg < 2; ++qg)
#pragma unroll
          for (int f = 0; f < 4; ++f) Oacc[qg][f] = z; }

    for (int j = 0; j < KTILES; ++j) {
        const int p  = j & 1;
        const int jn = (j + 1) & (KTILES - 1);

        // prefetch next V tile
        uint4 pv0 = *(const uint4*)(vbase + jn * 64);
        uint4 pv1 = *(const uint4*)(vbase + 32 * N_ + jn * 64);

        // phase A: S^T + exp (consumes ka)
        sh4 pfr[4][2];
#pragma unroll
        for (int f = 0; f < 4; ++f) {
#pragma unroll
            for (int qg = 0; qg < 2; ++qg) {
                floatx4 s = {0.f, 0.f, 0.f, 0.f};
                s = mfma32(ka[f][0], qf[qg][0], s);
                s = mfma32(ka[f][1], qf[qg][1], s);
                uint2 uu = { pk2(__builtin_amdgcn_exp2f(s[0]),
                                 __builtin_amdgcn_exp2f(s[1])),
                             pk2(__builtin_amdgcn_exp2f(s[2]),
                                 __builtin_amdgcn_exp2f(s[3])) };
                pfr[f][qg] = __builtin_bit_cast(sh4, uu);
            }
        }

        // phase B: reload ka for tile jn (latency hidden by phase C)
        {
            const unsigned short* kt = kslice + (size_t)jn * 64 * CI_;
#pragma unroll
            for (int f = 0; f < 4; ++f) {
                ka[f][0] = *(const short8*)(kt + (f * 16 + l15) * CI_ + quad * 8);
                ka[f][1] = *(const short8*)(kt + (f * 16 + l15) * CI_ + 32 + quad * 8);
            }
        }

        // phase C: PV + row sums from LDS
#pragma unroll
        for (int f = 0; f < 4; ++f) {
#pragma unroll
            for (int qg = 0; qg < 2; ++qg)
                lacc[qg] = mfma16(pfr[f][qg], ones4, lacc[qg]);
#pragma unroll
            for (int fc = 0; fc < 4; ++fc) {
                sh4 vb = *(const sh4*)&Vs[p][(fc * 16 + l15) * LDW + f * 16 + quad * 4];
#pragma unroll
                for (int qg = 0; qg < 2; ++qg)
                    Oacc[qg][fc] = mfma16(pfr[f][qg], vb, Oacc[qg][fc]);
            }
        }

        // commit V prefetch
        *(uint4*)&Vs[1 - p][srow * LDW + sc8 * 8]        = pv0;
        *(uint4*)&Vs[1 - p][(srow + 32) * LDW + sc8 * 8] = pv1;

        __syncthreads();
    }

    // epilogue: unnormalized partials, bf16
#pragma unroll
    for (int qg = 0; qg < 2; ++qg) {
#pragma unroll
        for (int r = 0; r < 4; ++r) {
            int row = q0 + w * 32 + qg * 16 + quad * 4 + r;
            size_t obase = ((size_t)(sp * B_ + b) * N_ + row) * CI_;
#pragma unroll
            for (int fc = 0; fc < 4; ++fc)
                Opart[obase + fc * 16 + l15] = f2bf(Oacc[qg][fc][r]);
            if (l15 == 0)
                lpart[(size_t)(sp * B_ + b) * N_ + row] = lacc[qg][r];
        }
    }
}

// ---------------------------------------------------------------------------
// Kernel 3: combine KSPLIT bf16 partials + w conv + bias + residual.
// v4: 2048 blocks (32-n tiles x 2 c-halves x 8 b) -> up to 8 blocks/CU.
// LDS aliased: weight phase (18.4KB bf16) / transpose phase (18.4KB fp32).
// ---------------------------------------------------------------------------
__global__ __launch_bounds__(256, 4) void out_kernel(
    const unsigned short* __restrict__ Opart, // [KSPLIT][B][N][CI] bf16
    const float* __restrict__ lpart,          // [KSPLIT][B][N]
    const float* __restrict__ ww,             // [C][CI]
    const float* __restrict__ wb,             // [C]
    const float* __restrict__ x,              // [B][C][N]
    float* __restrict__ out)                  // [B][C][N]
{
    constexpr int WS = 72;   // weight row stride (shorts)
    constexpr int TS = 36;   // transpose row stride (floats), 144B
    __shared__ __align__(16) char smem[128 * WS * 2];   // 18432B, aliased
    unsigned short* wws = (unsigned short*)smem;
    float*          T   = (float*)smem;

    const int t    = threadIdx.x;
    const int lane = t & 63;
    const int w    = t >> 6;
    const int l15  = lane & 15;
    const int quad = lane >> 4;
    const int n0   = blockIdx.x * 32;
    const int b    = blockIdx.y;
    const int ch   = blockIdx.z;             // c-half: rows ch*128..+128
    const int nf   = w & 1;                  // n-sub 16
    const int oh   = w >> 1;                 // oc 64-group

    // phase 1: stage W_w half -> bf16 LDS
#pragma unroll
    for (int it = 0; it < 8; ++it) {
        int u = t + it * 256;                // 2048 float4 units
        int row = u >> 4, c4 = u & 15;
        float4 v = *(const float4*)(ww + (ch * 128 + row) * CI_ + c4 * 4);
        uint2 uu = { pk2(v.x, v.y), pk2(v.z, v.w) };
        *(uint2*)&wws[row * WS + c4 * 4] = uu;
    }
    __syncthreads();

    floatx4 acc[4];
#pragma unroll
    for (int ot = 0; ot < 4; ++ot) { floatx4 z = {0.f, 0.f, 0.f, 0.f}; acc[ot] = z; }

    const int nB = n0 + nf * 16 + l15;
    float lsum = 0.f;
#pragma unroll
    for (int sp = 0; sp < KSPLIT; ++sp)
        lsum += lpart[(size_t)(sp * B_ + b) * N_ + nB];
    const float inv = 1.f / lsum;

#pragma unroll
    for (int ks = 0; ks < 2; ++ks) {
        float ysum[8] = {0.f, 0.f, 0.f, 0.f, 0.f, 0.f, 0.f, 0.f};
#pragma unroll
        for (int sp = 0; sp < KSPLIT; ++sp) {
            short8 ov = *(const short8*)(Opart +
                ((size_t)(sp * B_ + b) * N_ + nB) * CI_ + ks * 32 + quad * 8);
#pragma unroll
            for (int e = 0; e < 8; ++e)
                ysum[e] += bf2f((unsigned short)ov[e]);
        }
        uint4 bu = { pk2(ysum[0] * inv, ysum[1] * inv),
                     pk2(ysum[2] * inv, ysum[3] * inv),
                     pk2(ysum[4] * inv, ysum[5] * inv),
                     pk2(ysum[6] * inv, ysum[7] * inv) };
        short8 bfrag = __builtin_bit_cast(short8, bu);
#pragma unroll
        for (int ot = 0; ot < 4; ++ot) {
            short8 afrag = *(const short8*)&wws[(oh * 64 + ot * 16 + l15) * WS + ks * 32 + quad * 8];
            acc[ot] = mfma32(afrag, bfrag, acc[ot]);
        }
    }
    __syncthreads();   // done reading wws; smem becomes T

    // phase 2: acc + bias -> T[c][n] fp32
#pragma unroll
    for (int ot = 0; ot < 4; ++ot) {
#pragma unroll
        for (int r = 0; r < 4; ++r) {
            int cr = oh * 64 + ot * 16 + quad * 4 + r;
            T[cr * TS + nf * 16 + l15] = acc[ot][r] + wb[ch * 128 + cr];
        }
    }
    __syncthreads();

    // phase 3: coalesced float4 residual + store
#pragma unroll
    for (int it = 0; it < 4; ++it) {
        int u = t + it * 256;                // 1024 float4 units
        int row = u >> 3, col = u & 7;
        float4 tv = *(const float4*)&T[row * TS + col * 4];
        size_t idx = ((size_t)b * C_ + ch * 128 + row) * N_ + n0 + col * 4;
        float4 xv = *(const float4*)(x + idx);
        float4 ov = { tv.x + xv.x, tv.y + xv.y, tv.z + xv.z, tv.w + xv.w };
        *(float4*)(out + idx) = ov;
    }
}

extern "C" void kernel_launch(void* const* d_in, const int* in_sizes, int n_in,
                              void* d_out, int out_size, void* d_ws, size_t ws_size,
                              hipStream_t stream) {
    const float* x  = (const float*)d_in[0];
    const float* gw = (const float*)d_in[1];
    const float* gb = (const float*)d_in[2];
    const float* tw = (const float*)d_in[3];
    const float* tb = (const float*)d_in[4];
    const float* pw = (const float*)d_in[5];
    const float* pb = (const float*)d_in[6];
    const float* ww = (const float*)d_in[7];
    const float* wb = (const float*)d_in[8];
    float* out = (float*)d_out;

    char* ws = (char*)d_ws;
    unsigned short* gws   = (unsigned short*)(ws);              // 4MB   V^T bf16
    unsigned short* tws   = (unsigned short*)(ws + (4  << 20)); // 4MB   Q bf16
    unsigned short* pws   = (unsigned short*)(ws + (8  << 20)); // 4MB   K bf16
    unsigned short* Opart = (unsigned short*)(ws + (12 << 20)); // 16MB  O partials bf16
    float*          lpart = (float*)        (ws + (28 << 20));  // 512KB l partials

    proj_kernel<<<dim3(128, 8), 256, 0, stream>>>(x, gw, gb, tw, tb, pw, pb, gws, tws, pws);
    attn_kernel<<<dim3(8, 32, KSPLIT), 256, 0, stream>>>(gws, tws, pws, Opart, lpart);
    out_kernel<<<dim3(128, 8, 2), 256, 0, stream>>>(Opart, lpart, ww, wb, x, out);
}